// Round 1
// baseline (237.990 us; speedup 1.0000x reference)
//
#include <hip/hip_runtime.h>
#include <hip/hip_bf16.h>

#define SL 2048
#define NH 16
#define HD 128
#define EMB 2048

typedef __attribute__((ext_vector_type(8))) __bf16 bf16x8;
typedef __attribute__((ext_vector_type(4))) float f32x4;
typedef __attribute__((ext_vector_type(8))) short short8;

__device__ __forceinline__ short bf16bits(float x) {
  union { __hip_bfloat16 h; short s; } u;
  u.h = __float2bfloat16(x);
  return u.s;
}

#define GLDS16(gp, lp) __builtin_amdgcn_global_load_lds( \
    (__attribute__((address_space(1))) void*)(gp), \
    (__attribute__((address_space(3))) void*)(lp), 16, 0, 0)

// ---------------------------------------------------------------- casts
__global__ __launch_bounds__(256) void cast_f32_bf16(const float* __restrict__ in,
                                                     short* __restrict__ out, int n) {
  int i = (blockIdx.x * 256 + threadIdx.x) * 8;
  if (i >= n) return;
  float4 a = *(const float4*)(in + i);
  float4 b = *(const float4*)(in + i + 4);
  short8 o;
  o[0] = bf16bits(a.x); o[1] = bf16bits(a.y); o[2] = bf16bits(a.z); o[3] = bf16bits(a.w);
  o[4] = bf16bits(b.x); o[5] = bf16bits(b.y); o[6] = bf16bits(b.z); o[7] = bf16bits(b.w);
  *(short8*)(out + i) = o;
}

// ------------------------------------------------- m97-style NT GEMM, 128x128 tile
// C[m,n] = sum_k A[m,k]*B[n,k].  A:[M,2048] bf16, B:[N,2048] bf16 row-major.
// QV=1: grid x=17; tn<16 -> f32 C (ld 2048); tn==16 -> bf16 Vout (ld 128).
template<int QV>
__global__ __launch_bounds__(256) void gemm_bt(const short* __restrict__ A,
                                               const short* __restrict__ B,
                                               float* __restrict__ C,
                                               short* __restrict__ Vout) {
  __shared__ short As[128 * 32];
  __shared__ short Bs[128 * 32];
  const int K = 2048;
  int tn = blockIdx.x, tm = blockIdx.y;
  int tid = threadIdx.x;
  int wave = tid >> 6, lane = tid & 63;
  int g = lane >> 4, c = lane & 15;
  int wr = wave >> 1, wc = wave & 1;
  const short* Ab = A + (long)(tm * 128) * K;
  const short* Bb = B + (long)(tn * 128) * K;
  f32x4 zero = {0.f, 0.f, 0.f, 0.f};
  f32x4 acc[4][4];
#pragma unroll
  for (int m = 0; m < 4; ++m)
#pragma unroll
    for (int n = 0; n < 4; ++n) acc[m][n] = zero;

  for (int kt = 0; kt < K; kt += 32) {
    __syncthreads();
#pragma unroll
    for (int hh = 0; hh < 2; ++hh) {
      int rb = wave * 16 + hh * 64;                 // wave-uniform row base (16 rows = 1KB)
      GLDS16(Ab + (long)(rb + (lane >> 2)) * K + kt + (lane & 3) * 8, As + rb * 32);
      GLDS16(Bb + (long)(rb + (lane >> 2)) * K + kt + (lane & 3) * 8, Bs + rb * 32);
    }
    __syncthreads();
    bf16x8 a[4], b[4];
#pragma unroll
    for (int m = 0; m < 4; ++m) a[m] = *(const bf16x8*)(As + (wr * 64 + m * 16 + c) * 32 + g * 8);
#pragma unroll
    for (int n = 0; n < 4; ++n) b[n] = *(const bf16x8*)(Bs + (wc * 64 + n * 16 + c) * 32 + g * 8);
#pragma unroll
    for (int m = 0; m < 4; ++m)
#pragma unroll
      for (int n = 0; n < 4; ++n)
        acc[m][n] = __builtin_amdgcn_mfma_f32_16x16x32_bf16(a[m], b[n], acc[m][n], 0, 0, 0);
  }
  // epilogue: C layout col=lane&15, row=(lane>>4)*4+reg  [verified m89/m91]
  if (QV == 0 || tn < 16) {
#pragma unroll
    for (int m = 0; m < 4; ++m)
#pragma unroll
      for (int n = 0; n < 4; ++n)
#pragma unroll
        for (int r = 0; r < 4; ++r) {
          int row = tm * 128 + wr * 64 + m * 16 + g * 4 + r;
          int col = tn * 128 + wc * 64 + n * 16 + c;
          C[(long)row * 2048 + col] = acc[m][n][r];
        }
  } else {
#pragma unroll
    for (int m = 0; m < 4; ++m)
#pragma unroll
      for (int n = 0; n < 4; ++n)
#pragma unroll
        for (int r = 0; r < 4; ++r) {
          int row = tm * 128 + wr * 64 + m * 16 + g * 4 + r;
          int col = wc * 64 + n * 16 + c;
          Vout[(long)row * 128 + col] = bf16bits(acc[m][n][r]);
        }
  }
}

// ---------------------------------------- RMSNorm + double RoPE, one wave per (s,h)
__global__ __launch_bounds__(256) void rms_rope(const float* __restrict__ Q0,
                                                const float* __restrict__ cosT,
                                                const float* __restrict__ sinT,
                                                const float* __restrict__ gamma,
                                                short* __restrict__ Qb,
                                                short* __restrict__ Kb) {
  int wave = threadIdx.x >> 6, lane = threadIdx.x & 63;
  int idx = blockIdx.x * 4 + wave;   // idx = s*16 + h
  int s = idx >> 4, h = idx & 15;
  const float* qr = Q0 + (long)s * EMB + h * HD;
  float q1 = qr[lane], q2 = qr[lane + 64];
  float ss = q1 * q1 + q2 * q2;
#pragma unroll
  for (int off = 32; off >= 1; off >>= 1) ss += __shfl_xor(ss, off, 64);
  float rn = rsqrtf(ss * (1.0f / 128.0f) + 1e-6f);
  q1 *= rn * gamma[lane];
  q2 *= rn * gamma[lane + 64];
  float c1 = cosT[s * HD + lane], c2 = cosT[s * HD + lane + 64];
  float s1 = sinT[s * HD + lane], s2 = sinT[s * HD + lane + 64];
  // rope(x)[d<64] = x[d]*cos - x[d+64]*sin ; [d>=64] = x[d]*cos + x[d-64]*sin
  float Qr1 = q1 * c1 - q2 * s1;
  float Qr2 = q2 * c2 + q1 * s2;
  float Kr1 = Qr1 * c1 - Qr2 * s1;   // reference bug: K = rope(rope'd Q)
  float Kr2 = Qr2 * c2 + Qr1 * s2;
  long o = ((long)h * SL + s) * HD + lane;
  Qb[o] = bf16bits(Qr1); Qb[o + 64] = bf16bits(Qr2);
  Kb[o] = bf16bits(Kr1); Kb[o + 64] = bf16bits(Kr2);
}

// ---------------------------------------------------------- causal flash attention
// grid (32, 16): 64 q rows per block, 4 waves x 16 rows; KV tiles of 64.
__global__ __launch_bounds__(256) void attn(const short* __restrict__ Qb,
                                            const short* __restrict__ Kb,
                                            const short* __restrict__ Vb,
                                            short* __restrict__ att) {
  __shared__ short Ks[64 * 128];      // swizzled 16B chunks: lds(row,u) holds global(row, u^(row&7))
  __shared__ short Vt[128 * 72];      // V^T [d][kv], pad 72 (144B rows, 16B aligned)
  __shared__ short Ps[4][16 * 72];    // per-wave P [16 q][64 k], pad 72
  int wave = threadIdx.x >> 6, lane = threadIdx.x & 63;
  int g = lane >> 4, c = lane & 15;
  int h = blockIdx.y, qt = blockIdx.x;
  int qbase = qt * 64 + wave * 16;
  const short* Qh = Qb + (long)h * SL * HD;
  const short* Kh = Kb + (long)h * SL * HD;

  bf16x8 aq[4];
#pragma unroll
  for (int kc = 0; kc < 4; ++kc)
    aq[kc] = *(const bf16x8*)(Qh + (long)(qbase + c) * HD + kc * 32 + g * 8);

  float mrun[4], lrun[4];
#pragma unroll
  for (int r = 0; r < 4; ++r) { mrun[r] = -1e30f; lrun[r] = 0.f; }
  f32x4 zero = {0.f, 0.f, 0.f, 0.f};
  f32x4 O[8];
#pragma unroll
  for (int d8 = 0; d8 < 8; ++d8) O[d8] = zero;

  int ntile = qt + 1;
  for (int kt = 0; kt < ntile; ++kt) {
    int kvb = kt * 64;
    __syncthreads();
    // stage K tile (swizzled source -> linear LDS dest, rule #21)
#pragma unroll
    for (int i = 0; i < 4; ++i) {
      int rb = wave * 16 + i * 4;                  // 4 rows per 1KB load
      int row = rb + (lane >> 4);
      int c16 = (lane & 15) ^ (row & 7);
      GLDS16(Kh + (long)(kvb + row) * HD + c16 * 8, Ks + rb * 128);
    }
    // stage V transposed: lane = kv row (write side conflict-free)
#pragma unroll
    for (int j = 0; j < 4; ++j) {
      int d0 = wave * 32 + j * 8;
      short8 v = *(const short8*)(Vb + (long)(kvb + lane) * HD + d0);
#pragma unroll
      for (int i = 0; i < 8; ++i) Vt[(d0 + i) * 72 + lane] = v[i];
    }
    __syncthreads();

    // S = Q K^T
    f32x4 sf[4];
#pragma unroll
    for (int n = 0; n < 4; ++n) sf[n] = zero;
#pragma unroll
    for (int kc = 0; kc < 4; ++kc) {
#pragma unroll
      for (int n = 0; n < 4; ++n) {
        int row = n * 16 + c;
        int u = (kc * 4 + g) ^ (row & 7);
        bf16x8 bk = *(const bf16x8*)(Ks + row * 128 + u * 8);
        sf[n] = __builtin_amdgcn_mfma_f32_16x16x32_bf16(aq[kc], bk, sf[n], 0, 0, 0);
      }
    }

    const float sc = 0.08838834764831845f;   // 1/sqrt(128)
    float tmax[4];
#pragma unroll
    for (int r = 0; r < 4; ++r) tmax[r] = -1e30f;
#pragma unroll
    for (int n = 0; n < 4; ++n)
#pragma unroll
      for (int r = 0; r < 4; ++r) {
        int q = qbase + g * 4 + r;
        int k = kvb + n * 16 + c;
        float v = sf[n][r] * sc;
        if (k > q) v = -1e30f;
        sf[n][r] = v;
        tmax[r] = fmaxf(tmax[r], v);
      }
#pragma unroll
    for (int r = 0; r < 4; ++r) {
      tmax[r] = fmaxf(tmax[r], __shfl_xor(tmax[r], 1, 64));
      tmax[r] = fmaxf(tmax[r], __shfl_xor(tmax[r], 2, 64));
      tmax[r] = fmaxf(tmax[r], __shfl_xor(tmax[r], 4, 64));
      tmax[r] = fmaxf(tmax[r], __shfl_xor(tmax[r], 8, 64));
    }
    float corr[4];
#pragma unroll
    for (int r = 0; r < 4; ++r) {
      float mn = fmaxf(mrun[r], tmax[r]);
      corr[r] = __expf(mrun[r] - mn);
      mrun[r] = mn;
      lrun[r] *= corr[r];
    }
#pragma unroll
    for (int d8 = 0; d8 < 8; ++d8)
#pragma unroll
      for (int r = 0; r < 4; ++r) O[d8][r] *= corr[r];
    float rs[4] = {0.f, 0.f, 0.f, 0.f};
#pragma unroll
    for (int n = 0; n < 4; ++n)
#pragma unroll
      for (int r = 0; r < 4; ++r) {
        float p = __expf(sf[n][r] - mrun[r]);
        rs[r] += p;
        Ps[wave][(g * 4 + r) * 72 + n * 16 + c] = bf16bits(p);
      }
#pragma unroll
    for (int r = 0; r < 4; ++r) {
      rs[r] += __shfl_xor(rs[r], 1, 64);
      rs[r] += __shfl_xor(rs[r], 2, 64);
      rs[r] += __shfl_xor(rs[r], 4, 64);
      rs[r] += __shfl_xor(rs[r], 8, 64);
      lrun[r] += rs[r];
    }
    // O += P V   (P from per-wave LDS as A-frags, V^T as B-frags)
#pragma unroll
    for (int k2 = 0; k2 < 2; ++k2) {
      bf16x8 ap = *(const bf16x8*)(&Ps[wave][c * 72 + k2 * 32 + g * 8]);
#pragma unroll
      for (int d8 = 0; d8 < 8; ++d8) {
        bf16x8 bv = *(const bf16x8*)(Vt + (d8 * 16 + c) * 72 + k2 * 32 + g * 8);
        O[d8] = __builtin_amdgcn_mfma_f32_16x16x32_bf16(ap, bv, O[d8], 0, 0, 0);
      }
    }
  }
  // epilogue: att[q][h*128 + d]
#pragma unroll
  for (int d8 = 0; d8 < 8; ++d8)
#pragma unroll
    for (int r = 0; r < 4; ++r) {
      int q = qbase + g * 4 + r;
      float val = O[d8][r] / lrun[r];
      att[(long)q * EMB + h * HD + d8 * 16 + c] = bf16bits(val);
    }
}

// ---------------------------------------------------------------------- launch
extern "C" void kernel_launch(void* const* d_in, const int* in_sizes, int n_in,
                              void* d_out, int out_size, void* d_ws, size_t ws_size,
                              hipStream_t stream) {
  const float* x    = (const float*)d_in[0];
  const float* cosT = (const float*)d_in[1];
  const float* sinT = (const float*)d_in[2];
  const float* Wq   = (const float*)d_in[3];
  // d_in[4] = Wk  : dead code in reference
  const float* Wv   = (const float*)d_in[5];
  const float* Wo   = (const float*)d_in[6];
  const float* qg   = (const float*)d_in[7];
  // d_in[8] = k_gamma : dead code in reference

  char* w = (char*)d_ws;
  short* xb   = (short*)(w + 0);          //  8.0 MB  x bf16 [2048][2048]
  short* wqvb = (short*)(w + 8388608);    //  8.5 MB  [Wq;Wv] bf16 [2176][2048]
  short* wob  = (short*)(w + 17301504);   //  8.0 MB  Wo bf16
  float* q0   = (float*)(w + 25690112);   // 16.0 MB  Q0 f32 [2048][2048]
  short* vb   = (short*)(w + 42467328);   //  0.5 MB  V bf16 [2048][128]
  short* qb   = (short*)(w + 42991616);   //  8.0 MB  Q roped bf16 [16][2048][128]
  short* kb   = (short*)(w + 51380224);   //  8.0 MB  K roped bf16 [16][2048][128]
  short* attb = (short*)(w + 59768832);   //  8.0 MB  att bf16 [2048][2048]

  cast_f32_bf16<<<dim3(2048), dim3(256), 0, stream>>>(x,  xb,   4194304);
  cast_f32_bf16<<<dim3(2048), dim3(256), 0, stream>>>(Wq, wqvb, 4194304);
  cast_f32_bf16<<<dim3(128),  dim3(256), 0, stream>>>(Wv, wqvb + 4194304, 262144);
  cast_f32_bf16<<<dim3(2048), dim3(256), 0, stream>>>(Wo, wob,  4194304);

  gemm_bt<1><<<dim3(17, 16), dim3(256), 0, stream>>>(xb, wqvb, q0, vb);
  rms_rope<<<dim3(8192), dim3(256), 0, stream>>>(q0, cosT, sinT, qg, qb, kb);
  attn<<<dim3(32, 16), dim3(256), 0, stream>>>(qb, kb, vb, attb);
  gemm_bt<0><<<dim3(16, 16), dim3(256), 0, stream>>>(attb, wob, (float*)d_out, nullptr);
}

// Round 2
// 212.037 us; speedup vs baseline: 1.1224x; 1.1224x over previous
//
#include <hip/hip_runtime.h>
#include <hip/hip_bf16.h>

#define SL 2048
#define NH 16
#define HD 128
#define EMB 2048

typedef __attribute__((ext_vector_type(8))) __bf16 bf16x8;
typedef __attribute__((ext_vector_type(4))) float f32x4;
typedef __attribute__((ext_vector_type(8))) short short8;

__device__ __forceinline__ short bf16bits(float x) {
  union { __hip_bfloat16 h; short s; } u;
  u.h = __float2bfloat16(x);
  return u.s;
}

#define GLDS16(gp, lp) __builtin_amdgcn_global_load_lds( \
    (__attribute__((address_space(1))) void*)(gp), \
    (__attribute__((address_space(3))) void*)(lp), 16, 0, 0)

// ---------------------------------------------------------------- casts
__global__ __launch_bounds__(256) void cast_f32_bf16(const float* __restrict__ in,
                                                     short* __restrict__ out, int n) {
  int i = (blockIdx.x * 256 + threadIdx.x) * 8;
  if (i >= n) return;
  float4 a = *(const float4*)(in + i);
  float4 b = *(const float4*)(in + i + 4);
  short8 o;
  o[0] = bf16bits(a.x); o[1] = bf16bits(a.y); o[2] = bf16bits(a.z); o[3] = bf16bits(a.w);
  o[4] = bf16bits(b.x); o[5] = bf16bits(b.y); o[6] = bf16bits(b.z); o[7] = bf16bits(b.w);
  *(short8*)(out + i) = o;
}

// ------------------------------------------------- m97-style NT GEMM, 128x128 tile
template<int QV>
__global__ __launch_bounds__(256) void gemm_bt(const short* __restrict__ A,
                                               const short* __restrict__ B,
                                               float* __restrict__ C,
                                               short* __restrict__ Vout) {
  __shared__ short As[128 * 32];
  __shared__ short Bs[128 * 32];
  const int K = 2048;
  int tn = blockIdx.x, tm = blockIdx.y;
  int tid = threadIdx.x;
  int wave = tid >> 6, lane = tid & 63;
  int g = lane >> 4, c = lane & 15;
  int wr = wave >> 1, wc = wave & 1;
  const short* Ab = A + (long)(tm * 128) * K;
  const short* Bb = B + (long)(tn * 128) * K;
  f32x4 zero = {0.f, 0.f, 0.f, 0.f};
  f32x4 acc[4][4];
#pragma unroll
  for (int m = 0; m < 4; ++m)
#pragma unroll
    for (int n = 0; n < 4; ++n) acc[m][n] = zero;

  for (int kt = 0; kt < K; kt += 32) {
    __syncthreads();
#pragma unroll
    for (int hh = 0; hh < 2; ++hh) {
      int rb = wave * 16 + hh * 64;
      GLDS16(Ab + (long)(rb + (lane >> 2)) * K + kt + (lane & 3) * 8, As + rb * 32);
      GLDS16(Bb + (long)(rb + (lane >> 2)) * K + kt + (lane & 3) * 8, Bs + rb * 32);
    }
    __syncthreads();
    bf16x8 a[4], b[4];
#pragma unroll
    for (int m = 0; m < 4; ++m) a[m] = *(const bf16x8*)(As + (wr * 64 + m * 16 + c) * 32 + g * 8);
#pragma unroll
    for (int n = 0; n < 4; ++n) b[n] = *(const bf16x8*)(Bs + (wc * 64 + n * 16 + c) * 32 + g * 8);
#pragma unroll
    for (int m = 0; m < 4; ++m)
#pragma unroll
      for (int n = 0; n < 4; ++n)
        acc[m][n] = __builtin_amdgcn_mfma_f32_16x16x32_bf16(a[m], b[n], acc[m][n], 0, 0, 0);
  }
  if (QV == 0 || tn < 16) {
#pragma unroll
    for (int m = 0; m < 4; ++m)
#pragma unroll
      for (int n = 0; n < 4; ++n)
#pragma unroll
        for (int r = 0; r < 4; ++r) {
          int row = tm * 128 + wr * 64 + m * 16 + g * 4 + r;
          int col = tn * 128 + wc * 64 + n * 16 + c;
          C[(long)row * 2048 + col] = acc[m][n][r];
        }
  } else {
#pragma unroll
    for (int m = 0; m < 4; ++m)
#pragma unroll
      for (int n = 0; n < 4; ++n)
#pragma unroll
        for (int r = 0; r < 4; ++r) {
          int row = tm * 128 + wr * 64 + m * 16 + g * 4 + r;
          int col = wc * 64 + n * 16 + c;
          Vout[(long)row * 128 + col] = bf16bits(acc[m][n][r]);
        }
  }
}

// ---------------------------------------- RMSNorm + double RoPE, one wave per (s,h)
__global__ __launch_bounds__(256) void rms_rope(const float* __restrict__ Q0,
                                                const float* __restrict__ cosT,
                                                const float* __restrict__ sinT,
                                                const float* __restrict__ gamma,
                                                short* __restrict__ Qb,
                                                short* __restrict__ Kb) {
  int wave = threadIdx.x >> 6, lane = threadIdx.x & 63;
  int idx = blockIdx.x * 4 + wave;   // idx = s*16 + h
  int s = idx >> 4, h = idx & 15;
  const float* qr = Q0 + (long)s * EMB + h * HD;
  float q1 = qr[lane], q2 = qr[lane + 64];
  float ss = q1 * q1 + q2 * q2;
#pragma unroll
  for (int off = 32; off >= 1; off >>= 1) ss += __shfl_xor(ss, off, 64);
  float rn = rsqrtf(ss * (1.0f / 128.0f) + 1e-6f);
  q1 *= rn * gamma[lane];
  q2 *= rn * gamma[lane + 64];
  float c1 = cosT[s * HD + lane], c2 = cosT[s * HD + lane + 64];
  float s1 = sinT[s * HD + lane], s2 = sinT[s * HD + lane + 64];
  float Qr1 = q1 * c1 - q2 * s1;
  float Qr2 = q2 * c2 + q1 * s2;
  float Kr1 = Qr1 * c1 - Qr2 * s1;   // reference bug: K = rope(rope'd Q)
  float Kr2 = Qr2 * c2 + Qr1 * s2;
  long o = ((long)h * SL + s) * HD + lane;
  Qb[o] = bf16bits(Qr1); Qb[o + 64] = bf16bits(Qr2);
  Kb[o] = bf16bits(Kr1); Kb[o + 64] = bf16bits(Kr2);
}

// ---------------------------------------------------------- causal flash attention
// grid (32, 16): 64 q rows/block, 4 waves x 16 rows; KV tiles of 64.
// qt pairing: blocks (x,y) and (x,y^8) have complementary work -> each CU ~33 iters.
// K double-buffered via GLDS prefetch + counted vmcnt(8); V prefetched to regs (T14).
__global__ __launch_bounds__(256) void attn(const short* __restrict__ Qb,
                                            const short* __restrict__ Kb,
                                            const short* __restrict__ Vb,
                                            short* __restrict__ att) {
  __shared__ short Ks[2][64 * 128];   // swizzled: lds(row,u) holds global(row, u^(row&7))
  __shared__ short Vt[128 * 72];      // V^T [d][kv], pad 72
  __shared__ short Ps[4][16 * 72];    // per-wave P [16 q][64 k], pad 72
  int wave = threadIdx.x >> 6, lane = threadIdx.x & 63;
  int g = lane >> 4, c = lane & 15;
  int h = blockIdx.y;
  int qt = (blockIdx.y & 8) ? (31 - blockIdx.x) : blockIdx.x;
  int qbase = qt * 64 + wave * 16;
  const short* Qh = Qb + (long)h * SL * HD;
  const short* Kh = Kb + (long)h * SL * HD;

  bf16x8 aq[4];
#pragma unroll
  for (int kc = 0; kc < 4; ++kc)
    aq[kc] = *(const bf16x8*)(Qh + (long)(qbase + c) * HD + kc * 32 + g * 8);

  float mrun[4], lrun[4];
#pragma unroll
  for (int r = 0; r < 4; ++r) { mrun[r] = -1e30f; lrun[r] = 0.f; }
  f32x4 zero = {0.f, 0.f, 0.f, 0.f};
  f32x4 O[8];
#pragma unroll
  for (int d8 = 0; d8 < 8; ++d8) O[d8] = zero;

  int ntile = qt + 1;

  // ---- prologue: stage tile 0 (K -> Ks[0] via GLDS, V -> regs)
#pragma unroll
  for (int i = 0; i < 4; ++i) {
    int rb = wave * 16 + i * 4;
    int row = rb + (lane >> 4);
    int c16 = (lane & 15) ^ (row & 7);
    GLDS16(Kh + (long)row * HD + c16 * 8, &Ks[0][rb * 128]);
  }
  short8 vreg[4];
#pragma unroll
  for (int j = 0; j < 4; ++j)
    vreg[j] = *(const short8*)(Vb + (long)lane * HD + wave * 32 + j * 8);

  for (int kt = 0; kt < ntile; ++kt) {
    int kvb = kt * 64;
    int nxt = (kt + 1 < ntile) ? kt + 1 : kt;   // last iter: harmless refetch
    int bcu = kt & 1, bnx = (kt + 1) & 1;
    int kvn = nxt * 64;
    // issue next K tile
#pragma unroll
    for (int i = 0; i < 4; ++i) {
      int rb = wave * 16 + i * 4;
      int row = rb + (lane >> 4);
      int c16 = (lane & 15) ^ (row & 7);
      GLDS16(Kh + (long)(kvn + row) * HD + c16 * 8, &Ks[bnx][rb * 128]);
    }
    // issue next V tile -> regs
    short8 vnx[4];
#pragma unroll
    for (int j = 0; j < 4; ++j)
      vnx[j] = *(const short8*)(Vb + (long)(kvn + lane) * HD + wave * 32 + j * 8);

    asm volatile("s_waitcnt vmcnt(8)" ::: "memory");   // prev tile's 8 vmem done
    __builtin_amdgcn_s_barrier();                      // WAR: prev PV reads of Vt done

    // write V^T tile from regs (transpose scatter; 64-lane-contiguous: conflict-free)
#pragma unroll
    for (int j = 0; j < 4; ++j) {
      int d0 = wave * 32 + j * 8;
#pragma unroll
      for (int i = 0; i < 8; ++i) Vt[(d0 + i) * 72 + lane] = vreg[j][i];
    }
    asm volatile("s_waitcnt lgkmcnt(0)" ::: "memory");
    __builtin_amdgcn_s_barrier();                      // Vt + Ks[bcu] visible to all
    __builtin_amdgcn_sched_barrier(0);

    // S = Q K^T from Ks[bcu]
    f32x4 sf[4];
#pragma unroll
    for (int n = 0; n < 4; ++n) sf[n] = zero;
#pragma unroll
    for (int kc = 0; kc < 4; ++kc) {
#pragma unroll
      for (int n = 0; n < 4; ++n) {
        int row = n * 16 + c;
        int u = (kc * 4 + g) ^ (row & 7);
        bf16x8 bk = *(const bf16x8*)(&Ks[bcu][row * 128 + u * 8]);
        sf[n] = __builtin_amdgcn_mfma_f32_16x16x32_bf16(aq[kc], bk, sf[n], 0, 0, 0);
      }
    }

    const float sc = 0.08838834764831845f;   // 1/sqrt(128)
    float tmax[4];
#pragma unroll
    for (int r = 0; r < 4; ++r) tmax[r] = -1e30f;
#pragma unroll
    for (int n = 0; n < 4; ++n)
#pragma unroll
      for (int r = 0; r < 4; ++r) {
        int q = qbase + g * 4 + r;
        int k = kvb + n * 16 + c;
        float v = sf[n][r] * sc;
        if (k > q) v = -1e30f;
        sf[n][r] = v;
        tmax[r] = fmaxf(tmax[r], v);
      }
#pragma unroll
    for (int r = 0; r < 4; ++r) {
      tmax[r] = fmaxf(tmax[r], __shfl_xor(tmax[r], 1, 64));
      tmax[r] = fmaxf(tmax[r], __shfl_xor(tmax[r], 2, 64));
      tmax[r] = fmaxf(tmax[r], __shfl_xor(tmax[r], 4, 64));
      tmax[r] = fmaxf(tmax[r], __shfl_xor(tmax[r], 8, 64));
    }
    float corr[4];
#pragma unroll
    for (int r = 0; r < 4; ++r) {
      float mn = fmaxf(mrun[r], tmax[r]);
      corr[r] = __expf(mrun[r] - mn);
      mrun[r] = mn;
      lrun[r] *= corr[r];
    }
#pragma unroll
    for (int d8 = 0; d8 < 8; ++d8)
#pragma unroll
      for (int r = 0; r < 4; ++r) O[d8][r] *= corr[r];
    float rs[4] = {0.f, 0.f, 0.f, 0.f};
#pragma unroll
    for (int n = 0; n < 4; ++n)
#pragma unroll
      for (int r = 0; r < 4; ++r) {
        float p = __expf(sf[n][r] - mrun[r]);
        rs[r] += p;
        Ps[wave][(g * 4 + r) * 72 + n * 16 + c] = bf16bits(p);
      }
#pragma unroll
    for (int r = 0; r < 4; ++r) {
      rs[r] += __shfl_xor(rs[r], 1, 64);
      rs[r] += __shfl_xor(rs[r], 2, 64);
      rs[r] += __shfl_xor(rs[r], 4, 64);
      rs[r] += __shfl_xor(rs[r], 8, 64);
      lrun[r] += rs[r];
    }
    // O += P V
#pragma unroll
    for (int k2 = 0; k2 < 2; ++k2) {
      bf16x8 ap = *(const bf16x8*)(&Ps[wave][c * 72 + k2 * 32 + g * 8]);
#pragma unroll
      for (int d8 = 0; d8 < 8; ++d8) {
        bf16x8 bv = *(const bf16x8*)(Vt + (d8 * 16 + c) * 72 + k2 * 32 + g * 8);
        O[d8] = __builtin_amdgcn_mfma_f32_16x16x32_bf16(ap, bv, O[d8], 0, 0, 0);
      }
    }
    // rotate V prefetch regs
#pragma unroll
    for (int j = 0; j < 4; ++j) vreg[j] = vnx[j];
  }
  // epilogue
#pragma unroll
  for (int d8 = 0; d8 < 8; ++d8)
#pragma unroll
    for (int r = 0; r < 4; ++r) {
      int q = qbase + g * 4 + r;
      float val = O[d8][r] / lrun[r];
      att[(long)q * EMB + h * HD + d8 * 16 + c] = bf16bits(val);
    }
}

// ---------------------------------------------------------------------- launch
extern "C" void kernel_launch(void* const* d_in, const int* in_sizes, int n_in,
                              void* d_out, int out_size, void* d_ws, size_t ws_size,
                              hipStream_t stream) {
  const float* x    = (const float*)d_in[0];
  const float* cosT = (const float*)d_in[1];
  const float* sinT = (const float*)d_in[2];
  const float* Wq   = (const float*)d_in[3];
  const float* Wv   = (const float*)d_in[5];
  const float* Wo   = (const float*)d_in[6];
  const float* qg   = (const float*)d_in[7];

  char* w = (char*)d_ws;
  short* xb   = (short*)(w + 0);          //  8.0 MB  x bf16 [2048][2048]
  short* wqvb = (short*)(w + 8388608);    //  8.5 MB  [Wq;Wv] bf16 [2176][2048]
  short* wob  = (short*)(w + 17301504);   //  8.0 MB  Wo bf16
  float* q0   = (float*)(w + 25690112);   // 16.0 MB  Q0 f32
  short* vb   = (short*)(w + 42467328);   //  0.5 MB  V bf16 [2048][128]
  short* qb   = (short*)(w + 42991616);   //  8.0 MB  Q roped bf16 [16][2048][128]
  short* kb   = (short*)(w + 51380224);   //  8.0 MB  K roped bf16 [16][2048][128]
  short* attb = (short*)(w + 59768832);   //  8.0 MB  att bf16 [2048][2048]

  cast_f32_bf16<<<dim3(2048), dim3(256), 0, stream>>>(x,  xb,   4194304);
  cast_f32_bf16<<<dim3(2048), dim3(256), 0, stream>>>(Wq, wqvb, 4194304);
  cast_f32_bf16<<<dim3(128),  dim3(256), 0, stream>>>(Wv, wqvb + 4194304, 262144);
  cast_f32_bf16<<<dim3(2048), dim3(256), 0, stream>>>(Wo, wob,  4194304);

  gemm_bt<1><<<dim3(17, 16), dim3(256), 0, stream>>>(xb, wqvb, q0, vb);
  rms_rope<<<dim3(8192), dim3(256), 0, stream>>>(q0, cosT, sinT, qg, qb, kb);
  attn<<<dim3(32, 16), dim3(256), 0, stream>>>(qb, kb, vb, attb);
  gemm_bt<0><<<dim3(16, 16), dim3(256), 0, stream>>>(attb, wob, (float*)d_out, nullptr);
}